// Round 18
// baseline (482.093 us; speedup 1.0000x reference)
//
#include <hip/hip_runtime.h>
#include <hip/hip_fp16.h>
#include <math.h>

#define NEG_SLOPE 0.2f
#define BKT_SHIFT 8            // 256 nodes per bucket
#define EPB 8192               // edges per phase-A block
#define MAXB 10240             // record capacity per bucket region

__device__ __forceinline__ unsigned encf(float f) {
    unsigned u = __float_as_uint(f);
    return (u & 0x80000000u) ? ~u : (u | 0x80000000u);
}
__device__ __forceinline__ float decf(unsigned e) {
    unsigned u = (e & 0x80000000u) ? (e & 0x7FFFFFFFu) : ~e;
    return __uint_as_float(u);
}
__device__ __forceinline__ float lrelu(float t) { return fmaxf(t, NEG_SLOPE * t); }

// ---------------- node transform for conv1 + folded layer-1 amax (R17 verbatim) ----------------
__global__ __launch_bounds__(256) void k_node1(
        const float* __restrict__ x, const float* __restrict__ W1,
        const float* __restrict__ as1, const float* __restrict__ ad1,
        __half* __restrict__ h1h, float* __restrict__ a_src1,
        float* __restrict__ a_dst1, unsigned* __restrict__ amax, int N) {
    __shared__ float wmax[4][2];
    int tid = threadIdx.x;
    int n = blockIdx.x * blockDim.x + tid;
    float s0 = -1e30f, s1 = -1e30f;
    if (n < N) {
        float xv[8];
#pragma unroll
        for (int k = 0; k < 8; k++) xv[k] = x[n * 8 + k];
        float h[32];
#pragma unroll
        for (int j = 0; j < 32; j++) {
            float acc = 0.f;
#pragma unroll
            for (int k = 0; k < 8; k++) acc += xv[k] * W1[k * 32 + j];
            h[j] = acc;
            h1h[n * 32 + j] = __float2half(acc);
        }
        float sv[2];
#pragma unroll
        for (int hh = 0; hh < 2; hh++) {
            float s = 0.f, d = 0.f;
#pragma unroll
            for (int c = 0; c < 16; c++) {
                s += h[hh * 16 + c] * as1[hh * 16 + c];
                d += h[hh * 16 + c] * ad1[hh * 16 + c];
            }
            a_src1[n * 2 + hh] = s;
            a_dst1[n * 2 + hh] = d;
            sv[hh] = s;
        }
        s0 = sv[0]; s1 = sv[1];
    }
#pragma unroll
    for (int off = 32; off >= 1; off >>= 1) {
        s0 = fmaxf(s0, __shfl_xor(s0, off));
        s1 = fmaxf(s1, __shfl_xor(s1, off));
    }
    if ((tid & 63) == 0) { wmax[tid >> 6][0] = s0; wmax[tid >> 6][1] = s1; }
    __syncthreads();
    if (tid == 0) {
        float m0 = fmaxf(fmaxf(wmax[0][0], wmax[1][0]), fmaxf(wmax[2][0], wmax[3][0]));
        float m1 = fmaxf(fmaxf(wmax[0][1], wmax[1][1]), fmaxf(wmax[2][1], wmax[3][1]));
        atomicMax(&amax[0], encf(m0));
        atomicMax(&amax[1], encf(m1));
    }
}

// ---------------- CSR build, phase A (R17 verbatim) ----------------
__global__ __launch_bounds__(256) void k_bktA(const int* __restrict__ ei,
                                              int* __restrict__ bktCur,
                                              int2* __restrict__ bktbuf, int E, int K) {
    __shared__ int bh[256];
    __shared__ int bbase[256];
    __shared__ int loff[256];
    __shared__ int2 staged[EPB];
    __shared__ int gptr[EPB];
    int tid = threadIdx.x;
    int e0 = blockIdx.x * EPB;
    int e1 = e0 + EPB; if (e1 > E) e1 = E;
    int cnt = e1 - e0;
    bh[tid] = 0;
    __syncthreads();
    for (int i = e0 + tid; i < e1; i += 256)
        atomicAdd(&bh[ei[E + i] >> BKT_SHIFT], 1);
    __syncthreads();
    if (tid == 0) {
        int r = 0;
        for (int b = 0; b < K; b++) { loff[b] = r; r += bh[b]; }
    }
    if (tid < K) {
        int c = bh[tid];
        bbase[tid] = c > 0 ? atomicAdd(&bktCur[tid], c) : 0;
    }
    __syncthreads();
    bh[tid] = 0;
    __syncthreads();
    for (int i = e0 + tid; i < e1; i += 256) {
        int s = ei[i], d = ei[E + i];
        int b = d >> BKT_SHIFT, dl = d & 255;
        int r = atomicAdd(&bh[b], 1);
        int lp = loff[b] + r;
        staged[lp] = make_int2(s | (dl << 16), i);
        gptr[lp] = b * MAXB + bbase[b] + r;
    }
    __syncthreads();
    for (int i = tid; i < cnt; i += 256)
        bktbuf[gptr[i]] = staged[i];
}

// ---------------- CSR build, phase B: self-scan of bktCur prefix (no k_bktscan) ----------------
__global__ __launch_bounds__(256) void k_bktB(const int* __restrict__ bktCur,
                                              const int2* __restrict__ bktbuf,
                                              int* __restrict__ rowp, int2* __restrict__ slotv,
                                              int N, int E, int K) {
    __shared__ int lhist[256];
    __shared__ int lrow[257];
    __shared__ int2 lslot[MAXB + 256];
    __shared__ int sOff;
    int k = blockIdx.x;
    int tid = threadIdx.x;
    int n0 = k << BKT_SHIFT;
    int nn = N - n0; if (nn > 256) nn = 256;
    int cnt = bktCur[k];
    // prefix = sum of bktCur[0..k) computed locally (L2-hot, 64-lane strided)
    if (tid < 64) {
        int s = 0;
        for (int i = tid; i < k; i += 64) s += bktCur[i];
#pragma unroll
        for (int off = 32; off >= 1; off >>= 1) s += __shfl_xor(s, off);
        if (tid == 0) sOff = s;
    }
    lhist[tid] = 0;
    __syncthreads();
    int gbase = sOff + n0;
    const int2* rec = bktbuf + (size_t)k * MAXB;
    for (int i = tid; i < cnt; i += 256)
        atomicAdd(&lhist[(rec[i].x >> 16) & 255], 1);
    __syncthreads();
    if (tid == 0) {
        int r = 0;
        for (int i = 0; i < nn; i++) { lrow[i] = r; r += lhist[i] + 1; }
        lrow[nn] = r;
    }
    __syncthreads();
    if (tid < nn) {
        int lr = lrow[tid];
        rowp[n0 + tid] = gbase + lr;
        unsigned nd = (unsigned)(n0 + tid);
        lslot[lr] = make_int2((int)(nd | (nd << 16)), -1);   // self-loop: s=d=n
        lhist[tid] = lr + 1;
    }
    if (k == 0 && tid == 0) rowp[N] = E + N;
    __syncthreads();
    for (int i = tid; i < cnt; i += 256) {
        int2 rv = rec[i];
        int dl = (rv.x >> 16) & 255;
        int p = atomicAdd(&lhist[dl], 1);
        unsigned d = (unsigned)(n0 + dl);
        lslot[p] = make_int2((int)((unsigned)(rv.x & 0xFFFF) | (d << 16)), rv.y);
    }
    __syncthreads();
    int tot = cnt + nn;
    for (int i = tid; i < tot; i += 256)
        slotv[gbase + i] = lslot[i];
}

// ---------------- conv1 + node2 fused + folded layer-2 amax ----------------
__global__ __launch_bounds__(256) void k_conv1(
        const int* __restrict__ rowp, const int2* __restrict__ slotv,
        const float* __restrict__ a_src, const float* __restrict__ a_dst,
        const __half* __restrict__ h1h, const float* __restrict__ b1,
        const float* __restrict__ W2, const float* __restrict__ as2,
        const float* __restrict__ ad2,
        __half* __restrict__ h2h, float* __restrict__ a_src2,
        float* __restrict__ a_dst2, unsigned* __restrict__ amax, int N) {
    __shared__ int   lsS[4][64];
    __shared__ float lsW[4][2][80];       // stride 80: hh groups 16 banks apart
    __shared__ float wmax2[4][2];
    int tid = threadIdx.x;
    int lane = tid & 63;
    int wv = tid >> 6;
    int n = __builtin_amdgcn_readfirstlane((int)((blockIdx.x * blockDim.x + tid) >> 6));
    float sm0 = -1e30f, sm1 = -1e30f;     // layer-2 a_src max contribution
    if (n < N) {
        int q = lane >> 4;            // edge slot 0..3
        int c2 = lane & 15;           // channel pair 0..15
        int hh = c2 >> 3;             // head of this pair
        int beg = rowp[n], end = rowp[n + 1];
        float2 adv = *(const float2*)(a_dst + 2 * (size_t)n);
        float mA = lrelu(decf(amax[0]) + adv.x);
        float mB = lrelu(decf(amax[1]) + adv.y);
        float denom = 0.f;
        float accx = 0.f, accy = 0.f;
        for (int j0 = beg; j0 < end; j0 += 64) {
            int idx = j0 + lane;
            bool valid = idx < end;
            int s = valid ? (slotv[idx].x & 0xFFFF) : 0;
            float2 as = valid ? *(const float2*)(a_src + 2 * (size_t)s)
                              : make_float2(0.f, 0.f);
            float tA = lrelu(as.x + adv.x);
            float tB = lrelu(as.y + adv.y);
            float wA = valid ? __expf(tA - mA) : 0.f;
            float wB = valid ? __expf(tB - mB) : 0.f;
            lsS[wv][lane] = s;
            lsW[wv][0][lane] = wA;
            lsW[wv][1][lane] = wB;
            float rA = wA, rB = wB;
#pragma unroll
            for (int off = 32; off >= 1; off >>= 1) {
                rA += __shfl_xor(rA, off);
                rB += __shfl_xor(rB, off);
            }
            denom += hh ? rB : rA;
            int cnt = end - j0; if (cnt > 64) cnt = 64;
#pragma unroll 4
            for (int jj = 0; jj < cnt; jj += 4) {
                int e = jj + q;               // staged w=0 beyond cnt
                int sj = lsS[wv][e];
                float wgt = lsW[wv][hh][e];
                __half2 f = *(const __half2*)(h1h + sj * 32 + 2 * c2);
                float2 ff = __half22float2(f);
                accx += wgt * ff.x;
                accy += wgt * ff.y;
            }
        }
        accx += __shfl_xor(accx, 16); accy += __shfl_xor(accy, 16);
        accx += __shfl_xor(accx, 32); accy += __shfl_xor(accy, 32);
        float ovx = fmaxf(accx / denom + b1[2 * c2], 0.f);
        float ovy = fmaxf(accy / denom + b1[2 * c2 + 1], 0.f);
        float acc2 = 0.f;
#pragma unroll
        for (int p = 0; p < 16; p++) {
            acc2 += __shfl(ovx, p) * W2[(2 * p) * 64 + lane];
            acc2 += __shfl(ovy, p) * W2[(2 * p + 1) * 64 + lane];
        }
        h2h[(size_t)n * 64 + lane] = __float2half(acc2);
        float p = acc2 * as2[lane];
        float qd = acc2 * ad2[lane];
#pragma unroll
        for (int off = 16; off >= 1; off >>= 1) {
            p += __shfl_xor(p, off);
            qd += __shfl_xor(qd, off);
        }
        if ((lane & 31) == 0) {
            a_src2[n * 2 + (lane >> 5)] = p;
            a_dst2[n * 2 + (lane >> 5)] = qd;
        }
        sm0 = __shfl(p, 0);               // head-0 a_src2 value of this node
        sm1 = __shfl(p, 32);              // head-1
    }
    // block-level layer-2 amax reduce (all waves participate; inactive waves hold -1e30)
    if (lane == 0) { wmax2[wv][0] = sm0; wmax2[wv][1] = sm1; }
    __syncthreads();
    if (tid == 0) {
        float m0 = fmaxf(fmaxf(wmax2[0][0], wmax2[1][0]), fmaxf(wmax2[2][0], wmax2[3][0]));
        float m1 = fmaxf(fmaxf(wmax2[0][1], wmax2[1][1]), fmaxf(wmax2[2][1], wmax2[3][1]));
        atomicMax(&amax[2], encf(m0));
        atomicMax(&amax[3], encf(m1));
    }
}

// ---------------- conv2 + fc1 fused (R17 verbatim) ----------------
__global__ __launch_bounds__(256) void k_conv2(
        const int* __restrict__ rowp, const int2* __restrict__ slotv,
        const float* __restrict__ a_src, const float* __restrict__ a_dst,
        const __half* __restrict__ h2h, const float* __restrict__ b2,
        const float* __restrict__ fw1, const float* __restrict__ fb1,
        __half* __restrict__ gh, const unsigned* __restrict__ amax, int N) {
    __shared__ int   lsS[4][64];
    __shared__ float lsW[4][2][80];
    int tid = threadIdx.x;
    int lane = tid & 63;
    int wv = tid >> 6;
    int n = __builtin_amdgcn_readfirstlane((int)((blockIdx.x * blockDim.x + tid) >> 6));
    if (n >= N) return;
    int e2 = lane >> 5;           // edge slot 0..1
    int c2 = lane & 31;           // channel pair 0..31
    int hh = c2 >> 4;             // head of this pair
    int beg = rowp[n], end = rowp[n + 1];
    float2 adv = *(const float2*)(a_dst + 2 * (size_t)n);
    float mA = lrelu(decf(amax[0]) + adv.x);
    float mB = lrelu(decf(amax[1]) + adv.y);
    float denom = 0.f;
    float accx = 0.f, accy = 0.f;
    for (int j0 = beg; j0 < end; j0 += 64) {
        int idx = j0 + lane;
        bool valid = idx < end;
        int s = valid ? (slotv[idx].x & 0xFFFF) : 0;
        float2 as = valid ? *(const float2*)(a_src + 2 * (size_t)s)
                          : make_float2(0.f, 0.f);
        float tA = lrelu(as.x + adv.x);
        float tB = lrelu(as.y + adv.y);
        float wA = valid ? __expf(tA - mA) : 0.f;
        float wB = valid ? __expf(tB - mB) : 0.f;
        lsS[wv][lane] = s;
        lsW[wv][0][lane] = wA;
        lsW[wv][1][lane] = wB;
        float rA = wA, rB = wB;
#pragma unroll
        for (int off = 32; off >= 1; off >>= 1) {
            rA += __shfl_xor(rA, off);
            rB += __shfl_xor(rB, off);
        }
        denom += hh ? rB : rA;
        int cnt = end - j0; if (cnt > 64) cnt = 64;
#pragma unroll 8
        for (int jj = 0; jj < cnt; jj += 2) {
            int e = jj + e2;              // staged w=0 beyond cnt
            int sj = lsS[wv][e];
            float wgt = lsW[wv][hh][e];
            __half2 f = *(const __half2*)(h2h + (size_t)sj * 64 + 2 * c2);
            float2 ff = __half22float2(f);
            accx += wgt * ff.x;
            accy += wgt * ff.y;
        }
    }
    accx += __shfl_xor(accx, 32);
    accy += __shfl_xor(accy, 32);
    float resx = fmaxf(accx / denom + b2[2 * c2], 0.f);
    float resy = fmaxf(accy / denom + b2[2 * c2 + 1], 0.f);
    float gv = 0.5f * fb1[lane];
#pragma unroll
    for (int p = 0; p < 32; p++) {
        gv += __shfl(resx, p) * fw1[(2 * p) * 64 + lane];
        gv += __shfl(resy, p) * fw1[(2 * p + 1) * 64 + lane];
    }
    gh[(size_t)n * 64 + lane] = __float2half(gv);
}

// ---------------- edge head v5 (R17 verbatim) ----------------
__global__ void k_head4(const int2* __restrict__ slotv,
                        const __half* __restrict__ gh,
                        const float* __restrict__ w2, const float* __restrict__ b2,
                        float* __restrict__ out, int M) {
    int t = blockIdx.x * blockDim.x + threadIdx.x;
    if (t >= M) return;
    int2 sv = slotv[t];
    int id = sv.y;
    if (id < 0) return;
    int r = sv.x & 0xFFFF;
    int n = (int)(((unsigned)sv.x) >> 16);
    const uint4* gr = (const uint4*)(gh + (size_t)r * 64);
    const uint4* gc = (const uint4*)(gh + (size_t)n * 64);
    float o = b2[0];
#pragma unroll
    for (int qq = 0; qq < 8; qq++) {
        uint4 ua = gr[qq], ub = gc[qq];
#pragma unroll
        for (int w = 0; w < 4; w++) {
            unsigned a32 = (&ua.x)[w], b32 = (&ub.x)[w];
            float2 fa = __half22float2(*(const __half2*)&a32);
            float2 fb = __half22float2(*(const __half2*)&b32);
            int j = qq * 8 + w * 2;
            o += fmaxf(fa.x + fb.x, 0.f) * w2[j];
            o += fmaxf(fa.y + fb.y, 0.f) * w2[j + 1];
        }
    }
    out[id] = o;
}

extern "C" void kernel_launch(void* const* d_in, const int* in_sizes, int n_in,
                              void* d_out, int out_size, void* d_ws, size_t ws_size,
                              hipStream_t stream) {
    const float* x   = (const float*)d_in[0];
    const int*   ei  = (const int*)d_in[1];
    const float* W1  = (const float*)d_in[2];
    const float* as1 = (const float*)d_in[3];
    const float* ad1 = (const float*)d_in[4];
    const float* b1  = (const float*)d_in[5];
    const float* W2  = (const float*)d_in[6];
    const float* as2 = (const float*)d_in[7];
    const float* ad2 = (const float*)d_in[8];
    const float* b2  = (const float*)d_in[9];
    const float* fw1 = (const float*)d_in[10];
    const float* fb1 = (const float*)d_in[11];
    const float* fw2 = (const float*)d_in[12];
    const float* fb2 = (const float*)d_in[13];
    float* out = (float*)d_out;

    int N = in_sizes[0] / 8;
    int E = in_sizes[1] / 2;
    int M = E + N;
    int K = (N + 255) >> BKT_SHIFT;

    // ---- workspace layout (R17 verbatim) ----
    float* h1slot = (float*)d_ws;                       // holds h1h (fp16)
    float* asr1 = h1slot + (size_t)N * 32;
    float* adt1 = asr1 + (size_t)N * 2;
    float* out1 = adt1 + (size_t)N * 2;   // bktbuf home only
    float* h2slot = out1 + (size_t)N * 32;              // holds h2h (fp16)
    float* asr2 = h2slot + (size_t)N * 64;
    float* adt2 = asr2 + (size_t)N * 2;
    int*   rowp = (int*)(adt2 + (size_t)N * 2);
    int2*  slotv = (int2*)(rowp + ((N + 2) & ~1));
    int*   bktCur = (int*)(slotv + M);
    unsigned* amax = (unsigned*)(bktCur + 256);   // [0,1]=layer1, [2,3]=layer2
    int2*  bktbuf = (int2*)out1;          // dead after bktB
    __half* h1h = (__half*)h1slot;
    __half* h2h = (__half*)h2slot;
    __half* gh  = (__half*)d_ws;          // 64N halves over region A (dead post-conv1)

    int B = 256;
    hipMemsetAsync(bktCur, 0, 260 * sizeof(int), stream);   // bktCur + amax, BEFORE node1
    k_node1<<<(N + B - 1) / B, B, 0, stream>>>(x, W1, as1, ad1, h1h, asr1, adt1, amax, N);
    k_bktA<<<(E + EPB - 1) / EPB, 256, 0, stream>>>(ei, bktCur, bktbuf, E, K);
    k_bktB<<<K, 256, 0, stream>>>(bktCur, bktbuf, rowp, slotv, N, E, K);
    {
        long long thr = (long long)N * 64;
        k_conv1<<<(int)((thr + B - 1) / B), B, 0, stream>>>(rowp, slotv, asr1, adt1, h1h, b1,
                                                            W2, as2, ad2, h2h, asr2, adt2,
                                                            amax, N);
    }
    {
        long long thr = (long long)N * 64;
        k_conv2<<<(int)((thr + B - 1) / B), B, 0, stream>>>(rowp, slotv, asr2, adt2, h2h, b2,
                                                            fw1, fb1, gh, amax + 2, N);
    }
    k_head4<<<(M + B - 1) / B, B, 0, stream>>>(slotv, gh, fw2, fb2, out, M);
}

// Round 19
// 235.473 us; speedup vs baseline: 2.0473x; 2.0473x over previous
//
#include <hip/hip_runtime.h>
#include <hip/hip_fp16.h>
#include <math.h>

#define NEG_SLOPE 0.2f
#define BKT_SHIFT 8            // 256 nodes per bucket
#define EPB 8192               // edges per phase-A block
#define MAXB 10240             // record capacity per bucket region

__device__ __forceinline__ unsigned encf(float f) {
    unsigned u = __float_as_uint(f);
    return (u & 0x80000000u) ? ~u : (u | 0x80000000u);
}
__device__ __forceinline__ float decf(unsigned e) {
    unsigned u = (e & 0x80000000u) ? (e & 0x7FFFFFFFu) : ~e;
    return __uint_as_float(u);
}
__device__ __forceinline__ float lrelu(float t) { return fmaxf(t, NEG_SLOPE * t); }

// ---------------- node transform for conv1 + folded layer-1 amax (R17 verbatim) ----------------
__global__ __launch_bounds__(256) void k_node1(
        const float* __restrict__ x, const float* __restrict__ W1,
        const float* __restrict__ as1, const float* __restrict__ ad1,
        __half* __restrict__ h1h, float* __restrict__ a_src1,
        float* __restrict__ a_dst1, unsigned* __restrict__ amax, int N) {
    __shared__ float wmax[4][2];
    int tid = threadIdx.x;
    int n = blockIdx.x * blockDim.x + tid;
    float s0 = -1e30f, s1 = -1e30f;
    if (n < N) {
        float xv[8];
#pragma unroll
        for (int k = 0; k < 8; k++) xv[k] = x[n * 8 + k];
        float h[32];
#pragma unroll
        for (int j = 0; j < 32; j++) {
            float acc = 0.f;
#pragma unroll
            for (int k = 0; k < 8; k++) acc += xv[k] * W1[k * 32 + j];
            h[j] = acc;
            h1h[n * 32 + j] = __float2half(acc);
        }
        float sv[2];
#pragma unroll
        for (int hh = 0; hh < 2; hh++) {
            float s = 0.f, d = 0.f;
#pragma unroll
            for (int c = 0; c < 16; c++) {
                s += h[hh * 16 + c] * as1[hh * 16 + c];
                d += h[hh * 16 + c] * ad1[hh * 16 + c];
            }
            a_src1[n * 2 + hh] = s;
            a_dst1[n * 2 + hh] = d;
            sv[hh] = s;
        }
        s0 = sv[0]; s1 = sv[1];
    }
#pragma unroll
    for (int off = 32; off >= 1; off >>= 1) {
        s0 = fmaxf(s0, __shfl_xor(s0, off));
        s1 = fmaxf(s1, __shfl_xor(s1, off));
    }
    if ((tid & 63) == 0) { wmax[tid >> 6][0] = s0; wmax[tid >> 6][1] = s1; }
    __syncthreads();
    if (tid == 0) {
        float m0 = fmaxf(fmaxf(wmax[0][0], wmax[1][0]), fmaxf(wmax[2][0], wmax[3][0]));
        float m1 = fmaxf(fmaxf(wmax[0][1], wmax[1][1]), fmaxf(wmax[2][1], wmax[3][1]));
        atomicMax(&amax[0], encf(m0));
        atomicMax(&amax[1], encf(m1));
    }
}

// ---------------- global per-head max of a_src (layer 2; 64 blocks -> 128 atomics) ----------------
__global__ void k_amax(const float* __restrict__ a, unsigned* __restrict__ outmax, int N) {
    int lane = threadIdx.x & 63;
    float mA = -1e30f, mB = -1e30f;
    for (int i = blockIdx.x * blockDim.x + threadIdx.x; i < N; i += gridDim.x * blockDim.x) {
        float2 v = *(const float2*)(a + 2 * (size_t)i);
        mA = fmaxf(mA, v.x); mB = fmaxf(mB, v.y);
    }
#pragma unroll
    for (int off = 32; off >= 1; off >>= 1) {
        mA = fmaxf(mA, __shfl_xor(mA, off));
        mB = fmaxf(mB, __shfl_xor(mB, off));
    }
    if (lane == 0) {
        atomicMax(&outmax[0], encf(mA));
        atomicMax(&outmax[1], encf(mB));
    }
}

// ---------------- CSR build, phase A (R17 verbatim) ----------------
__global__ __launch_bounds__(256) void k_bktA(const int* __restrict__ ei,
                                              int* __restrict__ bktCur,
                                              int2* __restrict__ bktbuf, int E, int K) {
    __shared__ int bh[256];
    __shared__ int bbase[256];
    __shared__ int loff[256];
    __shared__ int2 staged[EPB];
    __shared__ int gptr[EPB];
    int tid = threadIdx.x;
    int e0 = blockIdx.x * EPB;
    int e1 = e0 + EPB; if (e1 > E) e1 = E;
    int cnt = e1 - e0;
    bh[tid] = 0;
    __syncthreads();
    for (int i = e0 + tid; i < e1; i += 256)
        atomicAdd(&bh[ei[E + i] >> BKT_SHIFT], 1);
    __syncthreads();
    if (tid == 0) {
        int r = 0;
        for (int b = 0; b < K; b++) { loff[b] = r; r += bh[b]; }
    }
    if (tid < K) {
        int c = bh[tid];
        bbase[tid] = c > 0 ? atomicAdd(&bktCur[tid], c) : 0;
    }
    __syncthreads();
    bh[tid] = 0;
    __syncthreads();
    for (int i = e0 + tid; i < e1; i += 256) {
        int s = ei[i], d = ei[E + i];
        int b = d >> BKT_SHIFT, dl = d & 255;
        int r = atomicAdd(&bh[b], 1);
        int lp = loff[b] + r;
        staged[lp] = make_int2(s | (dl << 16), i);
        gptr[lp] = b * MAXB + bbase[b] + r;
    }
    __syncthreads();
    for (int i = tid; i < cnt; i += 256)
        bktbuf[gptr[i]] = staged[i];
}

// ---------------- CSR build, phase B: self-scan of bktCur prefix (R18, proven) ----------------
__global__ __launch_bounds__(256) void k_bktB(const int* __restrict__ bktCur,
                                              const int2* __restrict__ bktbuf,
                                              int* __restrict__ rowp, int2* __restrict__ slotv,
                                              int N, int E, int K) {
    __shared__ int lhist[256];
    __shared__ int lrow[257];
    __shared__ int2 lslot[MAXB + 256];
    __shared__ int sOff;
    int k = blockIdx.x;
    int tid = threadIdx.x;
    int n0 = k << BKT_SHIFT;
    int nn = N - n0; if (nn > 256) nn = 256;
    int cnt = bktCur[k];
    if (tid < 64) {
        int s = 0;
        for (int i = tid; i < k; i += 64) s += bktCur[i];
#pragma unroll
        for (int off = 32; off >= 1; off >>= 1) s += __shfl_xor(s, off);
        if (tid == 0) sOff = s;
    }
    lhist[tid] = 0;
    __syncthreads();
    int gbase = sOff + n0;
    const int2* rec = bktbuf + (size_t)k * MAXB;
    for (int i = tid; i < cnt; i += 256)
        atomicAdd(&lhist[(rec[i].x >> 16) & 255], 1);
    __syncthreads();
    if (tid == 0) {
        int r = 0;
        for (int i = 0; i < nn; i++) { lrow[i] = r; r += lhist[i] + 1; }
        lrow[nn] = r;
    }
    __syncthreads();
    if (tid < nn) {
        int lr = lrow[tid];
        rowp[n0 + tid] = gbase + lr;
        unsigned nd = (unsigned)(n0 + tid);
        lslot[lr] = make_int2((int)(nd | (nd << 16)), -1);   // self-loop: s=d=n
        lhist[tid] = lr + 1;
    }
    if (k == 0 && tid == 0) rowp[N] = E + N;
    __syncthreads();
    for (int i = tid; i < cnt; i += 256) {
        int2 rv = rec[i];
        int dl = (rv.x >> 16) & 255;
        int p = atomicAdd(&lhist[dl], 1);
        unsigned d = (unsigned)(n0 + dl);
        lslot[p] = make_int2((int)((unsigned)(rv.x & 0xFFFF) | (d << 16)), rv.y);
    }
    __syncthreads();
    int tot = cnt + nn;
    for (int i = tid; i < tot; i += 256)
        slotv[gbase + i] = lslot[i];
}

// ---------------- conv1 + node2 fused (R17 verbatim, read-only amax) ----------------
__global__ __launch_bounds__(256) void k_conv1(
        const int* __restrict__ rowp, const int2* __restrict__ slotv,
        const float* __restrict__ a_src, const float* __restrict__ a_dst,
        const __half* __restrict__ h1h, const float* __restrict__ b1,
        const float* __restrict__ W2, const float* __restrict__ as2,
        const float* __restrict__ ad2,
        __half* __restrict__ h2h, float* __restrict__ a_src2,
        float* __restrict__ a_dst2, const unsigned* __restrict__ amax, int N) {
    __shared__ int   lsS[4][64];
    __shared__ float lsW[4][2][80];       // stride 80: hh groups 16 banks apart
    int tid = threadIdx.x;
    int lane = tid & 63;
    int wv = tid >> 6;
    int n = __builtin_amdgcn_readfirstlane((int)((blockIdx.x * blockDim.x + tid) >> 6));
    if (n >= N) return;
    int q = lane >> 4;            // edge slot 0..3
    int c2 = lane & 15;           // channel pair 0..15 (channels 2c2,2c2+1)
    int hh = c2 >> 3;             // head of this pair
    int beg = rowp[n], end = rowp[n + 1];
    float2 adv = *(const float2*)(a_dst + 2 * (size_t)n);
    float mA = lrelu(decf(amax[0]) + adv.x);
    float mB = lrelu(decf(amax[1]) + adv.y);
    float denom = 0.f;
    float accx = 0.f, accy = 0.f;
    for (int j0 = beg; j0 < end; j0 += 64) {
        int idx = j0 + lane;
        bool valid = idx < end;
        int s = valid ? (slotv[idx].x & 0xFFFF) : 0;
        float2 as = valid ? *(const float2*)(a_src + 2 * (size_t)s)
                          : make_float2(0.f, 0.f);
        float tA = lrelu(as.x + adv.x);
        float tB = lrelu(as.y + adv.y);
        float wA = valid ? __expf(tA - mA) : 0.f;
        float wB = valid ? __expf(tB - mB) : 0.f;
        lsS[wv][lane] = s;
        lsW[wv][0][lane] = wA;
        lsW[wv][1][lane] = wB;
        float rA = wA, rB = wB;
#pragma unroll
        for (int off = 32; off >= 1; off >>= 1) {
            rA += __shfl_xor(rA, off);
            rB += __shfl_xor(rB, off);
        }
        denom += hh ? rB : rA;
        int cnt = end - j0; if (cnt > 64) cnt = 64;
#pragma unroll 4
        for (int jj = 0; jj < cnt; jj += 4) {
            int e = jj + q;               // staged w=0 beyond cnt
            int sj = lsS[wv][e];
            float wgt = lsW[wv][hh][e];
            __half2 f = *(const __half2*)(h1h + sj * 32 + 2 * c2);
            float2 ff = __half22float2(f);
            accx += wgt * ff.x;
            accy += wgt * ff.y;
        }
    }
    accx += __shfl_xor(accx, 16); accy += __shfl_xor(accy, 16);
    accx += __shfl_xor(accx, 32); accy += __shfl_xor(accy, 32);
    float ovx = fmaxf(accx / denom + b1[2 * c2], 0.f);
    float ovy = fmaxf(accy / denom + b1[2 * c2 + 1], 0.f);
    float acc2 = 0.f;
#pragma unroll
    for (int p = 0; p < 16; p++) {
        acc2 += __shfl(ovx, p) * W2[(2 * p) * 64 + lane];
        acc2 += __shfl(ovy, p) * W2[(2 * p + 1) * 64 + lane];
    }
    h2h[(size_t)n * 64 + lane] = __float2half(acc2);
    float p = acc2 * as2[lane];
    float qd = acc2 * ad2[lane];
#pragma unroll
    for (int off = 16; off >= 1; off >>= 1) {
        p += __shfl_xor(p, off);
        qd += __shfl_xor(qd, off);
    }
    if ((lane & 31) == 0) {
        a_src2[n * 2 + (lane >> 5)] = p;
        a_dst2[n * 2 + (lane >> 5)] = qd;
    }
}

// ---------------- conv2 + fc1 fused (R17 verbatim) ----------------
__global__ __launch_bounds__(256) void k_conv2(
        const int* __restrict__ rowp, const int2* __restrict__ slotv,
        const float* __restrict__ a_src, const float* __restrict__ a_dst,
        const __half* __restrict__ h2h, const float* __restrict__ b2,
        const float* __restrict__ fw1, const float* __restrict__ fb1,
        __half* __restrict__ gh, const unsigned* __restrict__ amax, int N) {
    __shared__ int   lsS[4][64];
    __shared__ float lsW[4][2][80];
    int tid = threadIdx.x;
    int lane = tid & 63;
    int wv = tid >> 6;
    int n = __builtin_amdgcn_readfirstlane((int)((blockIdx.x * blockDim.x + tid) >> 6));
    if (n >= N) return;
    int e2 = lane >> 5;           // edge slot 0..1
    int c2 = lane & 31;           // channel pair 0..31
    int hh = c2 >> 4;             // head of this pair
    int beg = rowp[n], end = rowp[n + 1];
    float2 adv = *(const float2*)(a_dst + 2 * (size_t)n);
    float mA = lrelu(decf(amax[0]) + adv.x);
    float mB = lrelu(decf(amax[1]) + adv.y);
    float denom = 0.f;
    float accx = 0.f, accy = 0.f;
    for (int j0 = beg; j0 < end; j0 += 64) {
        int idx = j0 + lane;
        bool valid = idx < end;
        int s = valid ? (slotv[idx].x & 0xFFFF) : 0;
        float2 as = valid ? *(const float2*)(a_src + 2 * (size_t)s)
                          : make_float2(0.f, 0.f);
        float tA = lrelu(as.x + adv.x);
        float tB = lrelu(as.y + adv.y);
        float wA = valid ? __expf(tA - mA) : 0.f;
        float wB = valid ? __expf(tB - mB) : 0.f;
        lsS[wv][lane] = s;
        lsW[wv][0][lane] = wA;
        lsW[wv][1][lane] = wB;
        float rA = wA, rB = wB;
#pragma unroll
        for (int off = 32; off >= 1; off >>= 1) {
            rA += __shfl_xor(rA, off);
            rB += __shfl_xor(rB, off);
        }
        denom += hh ? rB : rA;
        int cnt = end - j0; if (cnt > 64) cnt = 64;
#pragma unroll 8
        for (int jj = 0; jj < cnt; jj += 2) {
            int e = jj + e2;              // staged w=0 beyond cnt
            int sj = lsS[wv][e];
            float wgt = lsW[wv][hh][e];
            __half2 f = *(const __half2*)(h2h + (size_t)sj * 64 + 2 * c2);
            float2 ff = __half22float2(f);
            accx += wgt * ff.x;
            accy += wgt * ff.y;
        }
    }
    accx += __shfl_xor(accx, 32);
    accy += __shfl_xor(accy, 32);
    float resx = fmaxf(accx / denom + b2[2 * c2], 0.f);
    float resy = fmaxf(accy / denom + b2[2 * c2 + 1], 0.f);
    float gv = 0.5f * fb1[lane];
#pragma unroll
    for (int p = 0; p < 32; p++) {
        gv += __shfl(resx, p) * fw1[(2 * p) * 64 + lane];
        gv += __shfl(resy, p) * fw1[(2 * p + 1) * 64 + lane];
    }
    gh[(size_t)n * 64 + lane] = __float2half(gv);
}

// ---------------- edge head v5 (R17 verbatim) ----------------
__global__ void k_head4(const int2* __restrict__ slotv,
                        const __half* __restrict__ gh,
                        const float* __restrict__ w2, const float* __restrict__ b2,
                        float* __restrict__ out, int M) {
    int t = blockIdx.x * blockDim.x + threadIdx.x;
    if (t >= M) return;
    int2 sv = slotv[t];
    int id = sv.y;
    if (id < 0) return;
    int r = sv.x & 0xFFFF;
    int n = (int)(((unsigned)sv.x) >> 16);
    const uint4* gr = (const uint4*)(gh + (size_t)r * 64);
    const uint4* gc = (const uint4*)(gh + (size_t)n * 64);
    float o = b2[0];
#pragma unroll
    for (int qq = 0; qq < 8; qq++) {
        uint4 ua = gr[qq], ub = gc[qq];
#pragma unroll
        for (int w = 0; w < 4; w++) {
            unsigned a32 = (&ua.x)[w], b32 = (&ub.x)[w];
            float2 fa = __half22float2(*(const __half2*)&a32);
            float2 fb = __half22float2(*(const __half2*)&b32);
            int j = qq * 8 + w * 2;
            o += fmaxf(fa.x + fb.x, 0.f) * w2[j];
            o += fmaxf(fa.y + fb.y, 0.f) * w2[j + 1];
        }
    }
    out[id] = o;
}

extern "C" void kernel_launch(void* const* d_in, const int* in_sizes, int n_in,
                              void* d_out, int out_size, void* d_ws, size_t ws_size,
                              hipStream_t stream) {
    const float* x   = (const float*)d_in[0];
    const int*   ei  = (const int*)d_in[1];
    const float* W1  = (const float*)d_in[2];
    const float* as1 = (const float*)d_in[3];
    const float* ad1 = (const float*)d_in[4];
    const float* b1  = (const float*)d_in[5];
    const float* W2  = (const float*)d_in[6];
    const float* as2 = (const float*)d_in[7];
    const float* ad2 = (const float*)d_in[8];
    const float* b2  = (const float*)d_in[9];
    const float* fw1 = (const float*)d_in[10];
    const float* fb1 = (const float*)d_in[11];
    const float* fw2 = (const float*)d_in[12];
    const float* fb2 = (const float*)d_in[13];
    float* out = (float*)d_out;

    int N = in_sizes[0] / 8;
    int E = in_sizes[1] / 2;
    int M = E + N;
    int K = (N + 255) >> BKT_SHIFT;

    // ---- workspace layout (R17 verbatim) ----
    float* h1slot = (float*)d_ws;                       // holds h1h (fp16)
    float* asr1 = h1slot + (size_t)N * 32;
    float* adt1 = asr1 + (size_t)N * 2;
    float* out1 = adt1 + (size_t)N * 2;   // bktbuf home only
    float* h2slot = out1 + (size_t)N * 32;              // holds h2h (fp16)
    float* asr2 = h2slot + (size_t)N * 64;
    float* adt2 = asr2 + (size_t)N * 2;
    int*   rowp = (int*)(adt2 + (size_t)N * 2);
    int2*  slotv = (int2*)(rowp + ((N + 2) & ~1));
    int*   bktCur = (int*)(slotv + M);
    unsigned* amax = (unsigned*)(bktCur + 256);   // [0,1]=layer1, [2,3]=layer2
    int2*  bktbuf = (int2*)out1;          // dead after bktB
    __half* h1h = (__half*)h1slot;
    __half* h2h = (__half*)h2slot;
    __half* gh  = (__half*)d_ws;          // 64N halves over region A (dead post-conv1)

    int B = 256;
    hipMemsetAsync(bktCur, 0, 260 * sizeof(int), stream);   // bktCur + amax, BEFORE node1
    k_node1<<<(N + B - 1) / B, B, 0, stream>>>(x, W1, as1, ad1, h1h, asr1, adt1, amax, N);
    k_bktA<<<(E + EPB - 1) / EPB, 256, 0, stream>>>(ei, bktCur, bktbuf, E, K);
    k_bktB<<<K, 256, 0, stream>>>(bktCur, bktbuf, rowp, slotv, N, E, K);
    {
        long long thr = (long long)N * 64;
        k_conv1<<<(int)((thr + B - 1) / B), B, 0, stream>>>(rowp, slotv, asr1, adt1, h1h, b1,
                                                            W2, as2, ad2, h2h, asr2, adt2,
                                                            amax, N);
    }
    k_amax<<<64, 256, 0, stream>>>(asr2, amax + 2, N);
    {
        long long thr = (long long)N * 64;
        k_conv2<<<(int)((thr + B - 1) / B), B, 0, stream>>>(rowp, slotv, asr2, adt2, h2h, b2,
                                                            fw1, fb1, gh, amax + 2, N);
    }
    k_head4<<<(M + B - 1) / B, B, 0, stream>>>(slotv, gh, fw2, fb2, out, M);
}